// Round 2
// baseline (415.992 us; speedup 1.0000x reference)
//
#include <hip/hip_runtime.h>

#define KCODES 512
#define DIM    64
#define HWPB   256   // H*W pixels per batch image = pixels per block

// --- prep: per-code squared norms ---------------------------------------
__global__ __launch_bounds__(256) void vq_prep(const float* __restrict__ e,
                                               float* __restrict__ enorm) {
    int j = blockIdx.x * blockDim.x + threadIdx.x;
    if (j < KCODES) {
        const float* er = e + j * DIM;
        float s = 0.f;
        #pragma unroll
        for (int d = 0; d < DIM; ++d) s = fmaf(er[d], er[d], s);
        enorm[j] = s;
    }
}

// --- main: one thread per pixel; z in VGPRs (float4[16]); e via wave-uniform
// scalar loads (SGPR operand of v_fmac — off the VMEM/LDS pipes entirely).
__global__ __launch_bounds__(256) void vq_main(
        const float* __restrict__ z, const float* __restrict__ e,
        const float* __restrict__ enorm, float* __restrict__ zq,
        float* __restrict__ counts)
{
    __shared__ int hist[KCODES];
    const int b  = blockIdx.x;
    const int hw = threadIdx.x;          // 0..255, this thread's pixel

    hist[hw]       = 0;
    hist[hw + 256] = 0;

    // Load this pixel's z vector into registers (coalesced across lanes per d).
    // float4[16] keeps the 64 floats in contiguous VGPR quads (no AGPR spill).
    const float* zb = z + (size_t)b * (DIM * HWPB) + hw;
    float4 zr[16];
    #pragma unroll
    for (int i = 0; i < 16; ++i) {
        zr[i].x = zb[(size_t)(4 * i + 0) * HWPB];
        zr[i].y = zb[(size_t)(4 * i + 1) * HWPB];
        zr[i].z = zb[(size_t)(4 * i + 2) * HWPB];
        zr[i].w = zb[(size_t)(4 * i + 3) * HWPB];
    }

    float bestv = 3.4e38f;
    int   besti = 0;

    // score = ||e_j||^2 - 2 z.e_j  (monotone-equal to ref dist; per-pixel
    // ||z||^2 dropped). Strict < ascending j == numpy first-min tie-break.
    #pragma unroll 2
    for (int j = 0; j < KCODES; ++j) {
        const float* __restrict__ er = e + (j << 6);  // wave-uniform address
        float a0 = 0.f, a1 = 0.f, a2 = 0.f, a3 = 0.f; // 4 indep FMA chains
        #pragma unroll
        for (int i = 0; i < 16; ++i) {
            float4 zv = zr[i];
            a0 = fmaf(zv.x, er[4 * i + 0], a0);
            a1 = fmaf(zv.y, er[4 * i + 1], a1);
            a2 = fmaf(zv.z, er[4 * i + 2], a2);
            a3 = fmaf(zv.w, er[4 * i + 3], a3);
        }
        float dot = (a0 + a1) + (a2 + a3);
        float s = fmaf(-2.f, dot, enorm[j]);
        if (s < bestv) { bestv = s; besti = j; }
    }

    __syncthreads();                 // hist init complete everywhere
    atomicAdd(&hist[besti], 1);

    // Gather the winning code row into z_q (stores coalesced across lanes).
    const float4* er4 = (const float4*)(e + besti * DIM);
    float* ob = zq + (size_t)b * (DIM * HWPB) + hw;
    #pragma unroll
    for (int i = 0; i < DIM / 4; ++i) {
        float4 v = er4[i];
        ob[(size_t)(4 * i + 0) * HWPB] = v.x;
        ob[(size_t)(4 * i + 1) * HWPB] = v.y;
        ob[(size_t)(4 * i + 2) * HWPB] = v.z;
        ob[(size_t)(4 * i + 3) * HWPB] = v.w;
    }

    __syncthreads();                 // all atomics into hist done
    int h0 = hist[hw];        if (h0) atomicAdd(&counts[hw],       (float)h0);
    int h1 = hist[hw + 256];  if (h1) atomicAdd(&counts[hw + 256], (float)h1);
}

// --- epilogue: EMA count update ------------------------------------------
__global__ __launch_bounds__(256) void vq_nupd(const float* __restrict__ N,
        const float* __restrict__ counts, float* __restrict__ outN) {
    int j = blockIdx.x * blockDim.x + threadIdx.x;
    if (j < KCODES) outN[j] = 0.995f * N[j] + 0.005f * counts[j];
}

extern "C" void kernel_launch(void* const* d_in, const int* in_sizes, int n_in,
                              void* d_out, int out_size, void* d_ws, size_t ws_size,
                              hipStream_t stream) {
    const float* z = (const float*)d_in[0];
    const float* e = (const float*)d_in[1];
    const float* N = (const float*)d_in[2];
    float* out = (float*)d_out;
    const int nz = in_sizes[0];               // B*D*H*W = 16777216
    const int B  = nz / (DIM * HWPB);         // 1024

    float* enorm  = (float*)d_ws;             // KCODES floats
    float* counts = enorm + KCODES;           // KCODES floats (ws is 0xAA-poisoned)

    hipMemsetAsync(counts, 0, KCODES * sizeof(float), stream);
    vq_prep<<<(KCODES + 255) / 256, 256, 0, stream>>>(e, enorm);
    vq_main<<<B, 256, 0, stream>>>(z, e, enorm, out, counts);
    vq_nupd<<<(KCODES + 255) / 256, 256, 0, stream>>>(N, counts, out + nz);
}

// Round 3
// 410.921 us; speedup vs baseline: 1.0123x; 1.0123x over previous
//
#include <hip/hip_runtime.h>

#define KCODES 512
#define DIM    64
#define HWPB   256   // H*W pixels per batch image = pixels per block

// --- prep: per-code squared norms ---------------------------------------
__global__ __launch_bounds__(256) void vq_prep(const float* __restrict__ e,
                                               float* __restrict__ enorm) {
    int j = blockIdx.x * blockDim.x + threadIdx.x;
    if (j < KCODES) {
        const float* er = e + j * DIM;
        float s = 0.f;
        #pragma unroll
        for (int d = 0; d < DIM; ++d) s = fmaf(er[d], er[d], s);
        enorm[j] = s;
    }
}

// --- main: one thread per pixel; z pinned in VGPRs; e via wave-uniform
// scalar loads (SGPR operand of v_fmac — off the VMEM/LDS pipes entirely).
__global__ __launch_bounds__(256) void vq_main(
        const float* __restrict__ z, const float* __restrict__ e,
        const float* __restrict__ enorm, float* __restrict__ zq,
        float* __restrict__ counts)
{
    __shared__ int hist[KCODES];
    const int b  = blockIdx.x;
    const int hw = threadIdx.x;          // 0..255, this thread's pixel

    hist[hw]       = 0;
    hist[hw + 256] = 0;

    // Load this pixel's z vector (coalesced across lanes for each d).
    const float* zb = z + (size_t)b * (DIM * HWPB) + hw;
    float zr[DIM];
    #pragma unroll
    for (int d = 0; d < DIM; ++d) zr[d] = zb[(size_t)d * HWPB];
    // Pin each value to a VGPR: blocks the compiler from sinking these
    // loop-invariant loads into the j-loop (rounds 1-2: it re-loaded all
    // 64 values from L2 every iteration -> VALUBusy 41%, dur 342us).
    #pragma unroll
    for (int d = 0; d < DIM; ++d) asm volatile("" : "+v"(zr[d]));

    float bestv = 3.4e38f;
    int   besti = 0;

    // score = ||e_j||^2 - 2 z.e_j  (monotone-equal to ref dist; per-pixel
    // ||z||^2 dropped). Strict < ascending j == numpy first-min tie-break.
    #pragma unroll 2
    for (int j = 0; j < KCODES; ++j) {
        const float* __restrict__ er = e + (j << 6);  // wave-uniform address
        float a0 = 0.f, a1 = 0.f, a2 = 0.f, a3 = 0.f; // 4 indep FMA chains
        #pragma unroll
        for (int d = 0; d < DIM; d += 4) {
            a0 = fmaf(zr[d + 0], er[d + 0], a0);
            a1 = fmaf(zr[d + 1], er[d + 1], a1);
            a2 = fmaf(zr[d + 2], er[d + 2], a2);
            a3 = fmaf(zr[d + 3], er[d + 3], a3);
        }
        float dot = (a0 + a1) + (a2 + a3);
        float s = fmaf(-2.f, dot, enorm[j]);
        if (s < bestv) { bestv = s; besti = j; }
    }

    __syncthreads();                 // hist init complete everywhere
    atomicAdd(&hist[besti], 1);

    // Gather the winning code row into z_q (stores coalesced across lanes).
    const float4* er4 = (const float4*)(e + besti * DIM);
    float* ob = zq + (size_t)b * (DIM * HWPB) + hw;
    #pragma unroll
    for (int i = 0; i < DIM / 4; ++i) {
        float4 v = er4[i];
        ob[(size_t)(4 * i + 0) * HWPB] = v.x;
        ob[(size_t)(4 * i + 1) * HWPB] = v.y;
        ob[(size_t)(4 * i + 2) * HWPB] = v.z;
        ob[(size_t)(4 * i + 3) * HWPB] = v.w;
    }

    __syncthreads();                 // all atomics into hist done
    int h0 = hist[hw];        if (h0) atomicAdd(&counts[hw],       (float)h0);
    int h1 = hist[hw + 256];  if (h1) atomicAdd(&counts[hw + 256], (float)h1);
}

// --- epilogue: EMA count update ------------------------------------------
__global__ __launch_bounds__(256) void vq_nupd(const float* __restrict__ N,
        const float* __restrict__ counts, float* __restrict__ outN) {
    int j = blockIdx.x * blockDim.x + threadIdx.x;
    if (j < KCODES) outN[j] = 0.995f * N[j] + 0.005f * counts[j];
}

extern "C" void kernel_launch(void* const* d_in, const int* in_sizes, int n_in,
                              void* d_out, int out_size, void* d_ws, size_t ws_size,
                              hipStream_t stream) {
    const float* z = (const float*)d_in[0];
    const float* e = (const float*)d_in[1];
    const float* N = (const float*)d_in[2];
    float* out = (float*)d_out;
    const int nz = in_sizes[0];               // B*D*H*W = 16777216
    const int B  = nz / (DIM * HWPB);         // 1024

    float* enorm  = (float*)d_ws;             // KCODES floats
    float* counts = enorm + KCODES;           // KCODES floats (ws is 0xAA-poisoned)

    hipMemsetAsync(counts, 0, KCODES * sizeof(float), stream);
    vq_prep<<<(KCODES + 255) / 256, 256, 0, stream>>>(e, enorm);
    vq_main<<<B, 256, 0, stream>>>(z, e, enorm, out, counts);
    vq_nupd<<<(KCODES + 255) / 256, 256, 0, stream>>>(N, counts, out + nz);
}

// Round 4
// 401.832 us; speedup vs baseline: 1.0352x; 1.0226x over previous
//
#include <hip/hip_runtime.h>

#define KCODES 512
#define DIM    64
#define HWPB   256   // H*W pixels per batch image = pixels per block

// (index, accumulator-chain) pairs for all 64 dims
#define FORALL(M) \
  M(0,0)  M(1,1)  M(2,2)  M(3,3)  M(4,0)  M(5,1)  M(6,2)  M(7,3) \
  M(8,0)  M(9,1)  M(10,2) M(11,3) M(12,0) M(13,1) M(14,2) M(15,3) \
  M(16,0) M(17,1) M(18,2) M(19,3) M(20,0) M(21,1) M(22,2) M(23,3) \
  M(24,0) M(25,1) M(26,2) M(27,3) M(28,0) M(29,1) M(30,2) M(31,3) \
  M(32,0) M(33,1) M(34,2) M(35,3) M(36,0) M(37,1) M(38,2) M(39,3) \
  M(40,0) M(41,1) M(42,2) M(43,3) M(44,0) M(45,1) M(46,2) M(47,3) \
  M(48,0) M(49,1) M(50,2) M(51,3) M(52,0) M(53,1) M(54,2) M(55,3) \
  M(56,0) M(57,1) M(58,2) M(59,3) M(60,0) M(61,1) M(62,2) M(63,3)

// --- prep: per-code squared norms ---------------------------------------
__global__ __launch_bounds__(256) void vq_prep(const float* __restrict__ e,
                                               float* __restrict__ enorm) {
    int j = blockIdx.x * blockDim.x + threadIdx.x;
    if (j < KCODES) {
        const float* er = e + j * DIM;
        float s = 0.f;
        #pragma unroll
        for (int d = 0; d < DIM; ++d) s = fmaf(er[d], er[d], s);
        enorm[j] = s;
    }
}

// --- main: one thread per pixel. z lives in 64 NAMED scalars, each pinned
// by its own volatile asm (cannot be rematerialized/sunk into the j-loop —
// rounds 1-3 showed VGPR_Count=40, i.e. the compiler was streaming z from
// L1/L2 on every one of the 512 iterations; that was the 59% VALU stall).
// e rows ride the scalar path (s_load -> SGPR operand of v_fmac).
__global__ __launch_bounds__(256) void vq_main(
        const float* __restrict__ z, const float* __restrict__ e,
        const float* __restrict__ enorm, float* __restrict__ zq,
        float* __restrict__ counts)
{
    __shared__ int hist[KCODES];
    const int b  = blockIdx.x;
    const int hw = threadIdx.x;          // 0..255, this thread's pixel

    hist[hw]       = 0;
    hist[hw + 256] = 0;

    const float* zb = z + (size_t)b * (DIM * HWPB) + hw;

#define LOADZ(i, c) float z##i = zb[(size_t)(i) * HWPB];
    FORALL(LOADZ)
#undef LOADZ
#define PINZ(i, c) asm volatile("" : "+v"(z##i));
    FORALL(PINZ)
#undef PINZ

    float bestv = 3.4e38f;
    int   besti = 0;

    // score = ||e_j||^2 - 2 z.e_j  (monotone-equal to ref dist; per-pixel
    // ||z||^2 dropped). Strict < ascending j == numpy first-min tie-break.
    for (int j = 0; j < KCODES; ++j) {
        const float* __restrict__ er = e + (j << 6);  // wave-uniform address
        float a0 = 0.f, a1 = 0.f, a2 = 0.f, a3 = 0.f; // 4 indep FMA chains
#define FMAS(i, c) a##c = fmaf(z##i, er[i], a##c);
        FORALL(FMAS)
#undef FMAS
        float dot = (a0 + a1) + (a2 + a3);
        float s = fmaf(-2.f, dot, enorm[j]);
        if (s < bestv) { bestv = s; besti = j; }
    }

    __syncthreads();                 // hist init complete everywhere
    atomicAdd(&hist[besti], 1);

    // Gather the winning code row into z_q (stores coalesced across lanes).
    const float4* er4 = (const float4*)(e + besti * DIM);
    float* ob = zq + (size_t)b * (DIM * HWPB) + hw;
    #pragma unroll
    for (int i = 0; i < DIM / 4; ++i) {
        float4 v = er4[i];
        ob[(size_t)(4 * i + 0) * HWPB] = v.x;
        ob[(size_t)(4 * i + 1) * HWPB] = v.y;
        ob[(size_t)(4 * i + 2) * HWPB] = v.z;
        ob[(size_t)(4 * i + 3) * HWPB] = v.w;
    }

    __syncthreads();                 // all atomics into hist done
    int h0 = hist[hw];        if (h0) atomicAdd(&counts[hw],       (float)h0);
    int h1 = hist[hw + 256];  if (h1) atomicAdd(&counts[hw + 256], (float)h1);
}

// --- epilogue: EMA count update ------------------------------------------
__global__ __launch_bounds__(256) void vq_nupd(const float* __restrict__ N,
        const float* __restrict__ counts, float* __restrict__ outN) {
    int j = blockIdx.x * blockDim.x + threadIdx.x;
    if (j < KCODES) outN[j] = 0.995f * N[j] + 0.005f * counts[j];
}

extern "C" void kernel_launch(void* const* d_in, const int* in_sizes, int n_in,
                              void* d_out, int out_size, void* d_ws, size_t ws_size,
                              hipStream_t stream) {
    const float* z = (const float*)d_in[0];
    const float* e = (const float*)d_in[1];
    const float* N = (const float*)d_in[2];
    float* out = (float*)d_out;
    const int nz = in_sizes[0];               // B*D*H*W = 16777216
    const int B  = nz / (DIM * HWPB);         // 1024

    float* enorm  = (float*)d_ws;             // KCODES floats
    float* counts = enorm + KCODES;           // KCODES floats (ws is 0xAA-poisoned)

    hipMemsetAsync(counts, 0, KCODES * sizeof(float), stream);
    vq_prep<<<(KCODES + 255) / 256, 256, 0, stream>>>(e, enorm);
    vq_main<<<B, 256, 0, stream>>>(z, e, enorm, out, counts);
    vq_nupd<<<(KCODES + 255) / 256, 256, 0, stream>>>(N, counts, out + nz);
}

// Round 5
// 217.906 us; speedup vs baseline: 1.9090x; 1.8441x over previous
//
#include <hip/hip_runtime.h>

#define KCODES 512
#define DIM    64
#define PXB    128   // pixels per block

typedef __attribute__((ext_vector_type(8))) short  short8;   // 8 bf16 = 4 VGPRs
typedef __attribute__((ext_vector_type(4))) float  floatx4;  // MFMA C/D

__device__ inline unsigned short f2bf(float x) {             // RNE fp32->bf16
    unsigned u = __float_as_uint(x);
    return (unsigned short)((u + 0x7FFFu + ((u >> 16) & 1u)) >> 16);
}
__device__ inline float bf2f(unsigned short h) { return __uint_as_float(((unsigned)h) << 16); }

// --- prep 1: per-code squared norms (from ORIGINAL fp32 e) ---------------
__global__ __launch_bounds__(256) void vq_prep(const float* __restrict__ e,
                                               float* __restrict__ enorm) {
    int j = blockIdx.x * blockDim.x + threadIdx.x;
    if (j < KCODES) {
        const float* er = e + j * DIM;
        float s = 0.f;
        #pragma unroll
        for (int d = 0; d < DIM; ++d) s = fmaf(er[d], er[d], s);
        enorm[j] = s;
    }
}

// --- prep 2: e -> bf16 hi/lo of (-2*e) -----------------------------------
__global__ __launch_bounds__(256) void vq_cvt(const float* __restrict__ e,
        unsigned short* __restrict__ ehs, unsigned short* __restrict__ els) {
    int t = blockIdx.x * 256 + threadIdx.x;        // 0..KCODES*DIM-1
    float x = -2.f * e[t];
    unsigned short h = f2bf(x);
    ehs[t] = h;
    els[t] = f2bf(x - bf2f(h));
}

// --- main ----------------------------------------------------------------
// Scores S[code][pixel] = ||e||^2 - 2 z.e via 16x16x32 bf16 MFMA.
// A = (-2e) bf16 hi/lo (codes = M, register-resident), B = z bf16 hi/lo
// (pixels = N, staged in LDS). C init = ||e||^2, so C_final = score.
// 3 passes: eL*zh + eH*zl + eH*zh  (residual ~2e-5 — same argmin-flip class
// as fp32 reassociation, which already passes at absmax 3.38 / thr 11).
__global__ __launch_bounds__(256, 1) void vq_main(
        const float* __restrict__ z, const float* __restrict__ e,
        const unsigned short* __restrict__ ehs, const unsigned short* __restrict__ els,
        const float* __restrict__ enorm, float* __restrict__ zq,
        float* __restrict__ counts)
{
    __shared__ __align__(16) short lz[2][8][PXB][8];  // [hi/lo][dim-chunk][px][8] = 32 KB
    __shared__ float red_v[4][PXB];                   // per-wave best value
    __shared__ int   red_i[4][PXB];                   // per-wave best index
    __shared__ int   hist[KCODES];

    const int b    = blockIdx.x;
    const int t    = threadIdx.x;
    const int wave = t >> 6;
    const int lane = t & 63;
    const int n16  = lane & 15;     // N (pixel) / M (code) row within tile
    const int g4   = lane >> 4;     // k-group / C row-group

    hist[t] = 0; hist[t + 256] = 0;

    // ---- stage z: 256 threads cover 128 px x 64 dims; thread handles
    //      pixel (t&127), dim-chunks (t>>7)*4 .. +3. Coalesced global reads.
    const int spx = t & 127;
    const int gch = (t >> 7) * 4;
    {
        const int gp = b * PXB + spx;          // global pixel id
        const int bb = gp >> 8, hw = gp & 255; // batch image, position
        const float* zb = z + (size_t)bb * (DIM * 256) + hw;
        #pragma unroll
        for (int g = gch; g < gch + 4; ++g) {
            float v[8];
            #pragma unroll
            for (int i = 0; i < 8; ++i) v[i] = zb[(size_t)(8 * g + i) * 256];
            short8 hi, lo;
            #pragma unroll
            for (int i = 0; i < 8; ++i) {
                unsigned short h = f2bf(v[i]);
                hi[i] = (short)h;
                lo[i] = (short)f2bf(v[i] - bf2f(h));
            }
            *(short8*)(&lz[0][g][spx][0]) = hi;
            *(short8*)(&lz[1][g][spx][0]) = lo;
        }
    }

    // ---- A-operand: wave owns codes wbase..wbase+127 (8 tiles of 16).
    // Lane holds code (wbase+ct*16+n16), dims ks*32 + g4*8 .. +7.
    const int wbase = wave * 128;
    short8 eH[8][2], eL[8][2];
    #pragma unroll
    for (int ct = 0; ct < 8; ++ct) {
        const size_t crow = (size_t)(wbase + ct * 16 + n16) * DIM + g4 * 8;
        #pragma unroll
        for (int ks = 0; ks < 2; ++ks) {
            eH[ct][ks] = *(const short8*)(ehs + crow + ks * 32);
            eL[ct][ks] = *(const short8*)(els + crow + ks * 32);
        }
    }
    // C-init values: enorm at C rows (g4*4 + r)
    float en[8][4];
    #pragma unroll
    for (int ct = 0; ct < 8; ++ct)
        #pragma unroll
        for (int r = 0; r < 4; ++r)
            en[ct][r] = enorm[wbase + ct * 16 + g4 * 4 + r];

    __syncthreads();   // z staging + hist init complete

    const int idbase = wbase + g4 * 4;

    for (int pt = 0; pt < PXB / 16; ++pt) {
        const int px = pt * 16 + n16;
        // B-fragments for this pixel tile (dims ks*32 + g4*8 .. +7)
        short8 bh0 = *(short8*)(&lz[0][g4    ][px][0]);
        short8 bh1 = *(short8*)(&lz[0][4 + g4][px][0]);
        short8 bl0 = *(short8*)(&lz[1][g4    ][px][0]);
        short8 bl1 = *(short8*)(&lz[1][4 + g4][px][0]);

        float bestv = 3.4e38f;
        int   besti = 0;

        #pragma unroll
        for (int ct = 0; ct < 8; ++ct) {
            floatx4 C = {en[ct][0], en[ct][1], en[ct][2], en[ct][3]};
            // smallest-magnitude passes first for fp32 accumulation
            C = __builtin_amdgcn_mfma_f32_16x16x32_bf16(eL[ct][0], bh0, C, 0, 0, 0);
            C = __builtin_amdgcn_mfma_f32_16x16x32_bf16(eL[ct][1], bh1, C, 0, 0, 0);
            C = __builtin_amdgcn_mfma_f32_16x16x32_bf16(eH[ct][0], bl0, C, 0, 0, 0);
            C = __builtin_amdgcn_mfma_f32_16x16x32_bf16(eH[ct][1], bl1, C, 0, 0, 0);
            C = __builtin_amdgcn_mfma_f32_16x16x32_bf16(eH[ct][0], bh0, C, 0, 0, 0);
            C = __builtin_amdgcn_mfma_f32_16x16x32_bf16(eH[ct][1], bh1, C, 0, 0, 0);
            #pragma unroll
            for (int r = 0; r < 4; ++r) {      // ascending code id: strict <
                float s = C[r];                 // == first-min tie-break
                int  id = idbase + ct * 16 + r;
                if (s < bestv) { bestv = s; besti = id; }
            }
        }
        // reduce over the 4 lane-groups holding this pixel's other codes
        float v1 = __shfl_down(bestv, 32); int i1 = __shfl_down(besti, 32);
        if (v1 < bestv || (v1 == bestv && i1 < besti)) { bestv = v1; besti = i1; }
        v1 = __shfl_down(bestv, 16); i1 = __shfl_down(besti, 16);
        if (v1 < bestv || (v1 == bestv && i1 < besti)) { bestv = v1; besti = i1; }
        if (lane < 16) { red_v[wave][px] = bestv; red_i[wave][px] = besti; }
    }

    __syncthreads();   // all waves' per-128-code bests written

    // ---- combine 4 waves, histogram, publish final index ----
    if (t < PXB) {
        float bv = red_v[0][t]; int bi = red_i[0][t];
        #pragma unroll
        for (int w = 1; w < 4; ++w) {
            float v = red_v[w][t]; int i = red_i[w][t];
            if (v < bv || (v == bv && i < bi)) { bv = v; bi = i; }
        }
        atomicAdd(&hist[bi], 1);
        red_i[0][t] = bi;          // final index for the gather phase
    }
    __syncthreads();

    // ---- gather: 256 threads = 128 px x 2 dim-halves; coalesced stores ----
    {
        const int px = t & 127, dh = (t >> 7) * 32;
        const int bi = red_i[0][px];
        const int gp = b * PXB + px;
        const int bb = gp >> 8, hw = gp & 255;
        const float4* er4 = (const float4*)(e + bi * DIM + dh);
        float* ob = zq + (size_t)bb * (DIM * 256) + (size_t)dh * 256 + hw;
        #pragma unroll
        for (int i = 0; i < 8; ++i) {
            float4 v = er4[i];
            ob[(size_t)(4 * i + 0) * 256] = v.x;
            ob[(size_t)(4 * i + 1) * 256] = v.y;
            ob[(size_t)(4 * i + 2) * 256] = v.z;
            ob[(size_t)(4 * i + 3) * 256] = v.w;
        }
    }

    __syncthreads();   // hist final
    int h0 = hist[t];       if (h0) atomicAdd(&counts[t],       (float)h0);
    int h1 = hist[t + 256]; if (h1) atomicAdd(&counts[t + 256], (float)h1);
}

// --- epilogue: EMA count update ------------------------------------------
__global__ __launch_bounds__(256) void vq_nupd(const float* __restrict__ N,
        const float* __restrict__ counts, float* __restrict__ outN) {
    int j = blockIdx.x * blockDim.x + threadIdx.x;
    if (j < KCODES) outN[j] = 0.995f * N[j] + 0.005f * counts[j];
}

extern "C" void kernel_launch(void* const* d_in, const int* in_sizes, int n_in,
                              void* d_out, int out_size, void* d_ws, size_t ws_size,
                              hipStream_t stream) {
    const float* z = (const float*)d_in[0];
    const float* e = (const float*)d_in[1];
    const float* N = (const float*)d_in[2];
    float* out = (float*)d_out;
    const int nz     = in_sizes[0];            // B*D*H*W = 16777216
    const int npix   = nz / DIM;               // 262144
    const int blocks = npix / PXB;             // 2048

    char* ws = (char*)d_ws;
    float*          enorm  = (float*)(ws);                 // 512 f
    float*          counts = (float*)(ws + 2048);          // 512 f
    unsigned short* ehs    = (unsigned short*)(ws + 4096); // 32768 u16
    unsigned short* els    = (unsigned short*)(ws + 4096 + KCODES * DIM * 2);

    hipMemsetAsync(counts, 0, KCODES * sizeof(float), stream);
    vq_prep<<<(KCODES + 255) / 256, 256, 0, stream>>>(e, enorm);
    vq_cvt<<<(KCODES * DIM) / 256, 256, 0, stream>>>(e, ehs, els);
    vq_main<<<blocks, 256, 0, stream>>>(z, e, ehs, els, enorm, out, counts);
    vq_nupd<<<(KCODES + 255) / 256, 256, 0, stream>>>(N, counts, out + nz);
}